// Round 1
// baseline (1106.242 us; speedup 1.0000x reference)
//
#include <hip/hip_runtime.h>
#include <cstdint>

#define B_ 8
#define C_ 512
#define T_ 1500
#define N_ (B_*T_)      // 12000 tokens
#define V_ 4096
#define K_ 100

typedef unsigned long long u64;

// ---------------- small preps ----------------

__global__ void init_accum(float* accum){
    if (threadIdx.x < 2) accum[threadIdx.x] = 0.f;
}

// one wave per row: sum of squares of a 512-float row
__global__ __launch_bounds__(256) void rowsq_kernel(const float* __restrict__ X,
                                                    float* __restrict__ out, int rows){
    int wid = threadIdx.x >> 6, lane = threadIdx.x & 63;
    int r = blockIdx.x * 4 + wid;
    if (r >= rows) return;
    const float* p = X + (size_t)r * C_;
    float s = 0.f;
    #pragma unroll
    for (int j = 0; j < 8; ++j){ float v = p[lane + j*64]; s += v * v; }
    #pragma unroll
    for (int o = 32; o > 0; o >>= 1) s += __shfl_down(s, o, 64);
    if (lane == 0) out[r] = s;
}

// student_emb (B,C,T) -> embT (B*T, C) row-major
__global__ __launch_bounds__(256) void transpose_kernel(const float* __restrict__ S,
                                                        float* __restrict__ embT){
    __shared__ float tile[32][33];
    int b  = blockIdx.z;
    int c0 = blockIdx.y * 32;
    int t0 = blockIdx.x * 32;
    int tx = threadIdx.x, ty = threadIdx.y; // 32 x 8
    #pragma unroll
    for (int r = 0; r < 4; ++r){
        int c = c0 + ty + r*8;
        int t = t0 + tx;
        if (t < T_) tile[ty + r*8][tx] = S[((size_t)b*C_ + c)*T_ + t];
    }
    __syncthreads();
    #pragma unroll
    for (int r = 0; r < 4; ++r){
        int t = t0 + ty + r*8;
        int c = c0 + tx;
        if (t < T_) embT[((size_t)b*T_ + t)*C_ + c] = tile[tx][ty + r*8];
    }
}

// ---------------- fp32 distance GEMM ----------------
// dist[n - row_lo][v] = sqrt(max(||e_n||^2 + ||c_v||^2 - 2 e_n.c_v, 0))
// BM=BN=128, BK=8, 256 threads, 8x8 micro-tile
__global__ __launch_bounds__(256) void gemm_dist_kernel(
    const float* __restrict__ A, const float* __restrict__ Bm,
    const float* __restrict__ esq, const float* __restrict__ csq,
    float* __restrict__ dist, int row_lo, int row_hi)
{
    __shared__ float As[8][128];
    __shared__ float Bs[8][128];
    int tid = threadIdx.x;
    int lr = tid >> 1;           // 0..127 tile row for loads
    int lc = (tid & 1) * 4;      // 0 or 4 within the 8-wide k slab
    int row0 = row_lo + blockIdx.x * 128;
    int col0 = blockIdx.y * 128;
    int ty = tid >> 4, tx = tid & 15;

    float acc[8][8];
    #pragma unroll
    for (int i = 0; i < 8; ++i)
        #pragma unroll
        for (int j = 0; j < 8; ++j) acc[i][j] = 0.f;

    int ar = row0 + lr; if (ar > N_ - 1) ar = N_ - 1;   // clamp (guarded store)
    const float* Aptr = A  + (size_t)ar * C_ + lc;
    const float* Bptr = Bm + (size_t)(col0 + lr) * C_ + lc;

    for (int kt = 0; kt < C_/8; ++kt){
        float4 a4 = *(const float4*)(Aptr + kt*8);
        float4 b4 = *(const float4*)(Bptr + kt*8);
        __syncthreads();
        As[lc+0][lr] = a4.x; As[lc+1][lr] = a4.y; As[lc+2][lr] = a4.z; As[lc+3][lr] = a4.w;
        Bs[lc+0][lr] = b4.x; Bs[lc+1][lr] = b4.y; Bs[lc+2][lr] = b4.z; Bs[lc+3][lr] = b4.w;
        __syncthreads();
        #pragma unroll
        for (int k = 0; k < 8; ++k){
            float a[8], b[8];
            #pragma unroll
            for (int i = 0; i < 8; ++i) a[i] = As[k][ty*8 + i];
            #pragma unroll
            for (int j = 0; j < 8; ++j) b[j] = Bs[k][tx*8 + j];
            #pragma unroll
            for (int i = 0; i < 8; ++i)
                #pragma unroll
                for (int j = 0; j < 8; ++j) acc[i][j] = fmaf(a[i], b[j], acc[i][j]);
        }
    }

    #pragma unroll
    for (int i = 0; i < 8; ++i){
        int n = row0 + ty*8 + i;
        if (n >= row_hi) continue;
        float en = esq[n];
        #pragma unroll
        for (int j = 0; j < 8; ++j){
            int v = col0 + tx*8 + j;
            float d2 = en + csq[v] - 2.f * acc[i][j];
            dist[(size_t)(n - row_lo) * V_ + v] = sqrtf(fmaxf(d2, 0.f));
        }
    }
}

// ---------------- per-token selection + loss ----------------
// key = (float_bits(dist) << 12) | idx  -> exact jax top_k tie semantics
__global__ __launch_bounds__(256) void select_kernel(
    const float* __restrict__ dist, const int* __restrict__ codes,
    float* __restrict__ accum, int row_lo)
{
    int n   = row_lo + blockIdx.x;
    int tid = threadIdx.x;
    const float* row = dist + (size_t)blockIdx.x * V_;

    float d[16];
    #pragma unroll
    for (int i = 0; i < 16; ++i) d[i] = row[i*256 + tid];

    // ---- global min key (d0, idx0) ----
    u64 kmin = ~0ull;
    #pragma unroll
    for (int i = 0; i < 16; ++i){
        u64 key = ((u64)__float_as_uint(d[i]) << 12) | (unsigned)(i*256 + tid);
        if (key < kmin) kmin = key;
    }
    #pragma unroll
    for (int o = 32; o > 0; o >>= 1){
        u64 other = __shfl_down(kmin, o, 64);
        if (other < kmin) kmin = other;
    }
    __shared__ u64 wred[4];
    int wid = tid >> 6, lane = tid & 63;
    if (lane == 0) wred[wid] = kmin;
    __syncthreads();
    u64 gmin = wred[0];
    #pragma unroll
    for (int w = 1; w < 4; ++w) if (wred[w] < gmin) gmin = wred[w];

    float d0  = __uint_as_float((unsigned)(gmin >> 12));
    int idx0  = (int)(gmin & 0xFFFu);
    int code  = codes[n];
    float dcode = row[code];   // same-address broadcast load

    // ---- radix select: 100th smallest 44-bit key (rank 99) ----
    __shared__ unsigned hist[256];
    __shared__ unsigned scan[256];
    __shared__ u64 s_prefix;
    __shared__ int s_kk;
    if (tid == 0){ s_prefix = 0ull; s_kk = K_ - 1; }
    __syncthreads();

    #pragma unroll 1
    for (int pass = 0; pass < 6; ++pass){
        int shift = 40 - pass*8;
        hist[tid] = 0;
        __syncthreads();
        u64 pref = s_prefix; int kk = s_kk;
        #pragma unroll
        for (int i = 0; i < 16; ++i){
            u64 key = ((u64)__float_as_uint(d[i]) << 12) | (unsigned)(i*256 + tid);
            if ((key >> (shift + 8)) == pref)
                atomicAdd(&hist[(unsigned)(key >> shift) & 255u], 1u);
        }
        __syncthreads();
        // Hillis-Steele inclusive scan over 256 bins
        unsigned x = hist[tid];
        scan[tid] = x;
        __syncthreads();
        for (int o = 1; o < 256; o <<= 1){
            unsigned y = (tid >= o) ? scan[tid - o] : 0u;
            __syncthreads();
            scan[tid] += y;
            __syncthreads();
        }
        unsigned inc = scan[tid], exc = inc - x;
        if ((unsigned)kk >= exc && (unsigned)kk < inc){
            s_prefix = (pref << 8) | (unsigned)tid;
            s_kk = kk - (int)exc;
        }
        __syncthreads();
    }
    u64 T100 = s_prefix;   // exact 100th-smallest key

    // ---- sum exp(d0 - d_k) over the top-100 set ----
    float s = 0.f;
    #pragma unroll
    for (int i = 0; i < 16; ++i){
        u64 key = ((u64)__float_as_uint(d[i]) << 12) | (unsigned)(i*256 + tid);
        if (key <= T100) s += expf(d0 - d[i]);
    }
    #pragma unroll
    for (int o = 32; o > 0; o >>= 1) s += __shfl_down(s, o, 64);
    __shared__ float wsumf[4];
    if (lane == 0) wsumf[wid] = s;
    __syncthreads();

    if (tid == 0){
        float S = wsumf[0] + wsumf[1] + wsumf[2] + wsumf[3];
        u64 keycode = ((u64)__float_as_uint(dcode) << 12) | (unsigned)code;
        if (keycode > T100){
            // include_correct: swap the 100th candidate for the true code
            float dT = __uint_as_float((unsigned)(T100 >> 12));
            S += expf(d0 - dcode) - expf(d0 - dT);
        }
        float nll = dcode - d0 + logf(S);   // -log_softmax at the label
        atomicAdd(&accum[0], nll);
        atomicAdd(&accum[1], (idx0 == code) ? 1.f : 0.f);
    }
}

__global__ void finalize_kernel(const float* __restrict__ accum, float* __restrict__ out){
    float loss = accum[0] / (float)N_;
    float acc  = accum[1] / (float)N_;
    out[0] = loss;
    out[1] = acc;   // local_accuracy: prediction is always slot 0 -> == global_accuracy
    out[2] = acc;   // global_accuracy
    out[3] = 1.0f;  // correct_in_candidates: guaranteed by the include-correct swap
}

// ---------------- launcher ----------------

extern "C" void kernel_launch(void* const* d_in, const int* in_sizes, int n_in,
                              void* d_out, int out_size, void* d_ws, size_t ws_size,
                              hipStream_t stream){
    const float* S   = (const float*)d_in[0];   // (8,512,1500) fp32
    const int* codes = (const int*)d_in[1];     // (8,1500) int
    const float* CB  = (const float*)d_in[2];   // (4096,512) fp32
    float* out = (float*)d_out;

    char* w = (char*)d_ws;
    size_t off = 0;
    float* embT = (float*)(w + off); off += (size_t)N_ * C_ * sizeof(float);
    float* csq  = (float*)(w + off); off += (size_t)V_ * sizeof(float);
    float* esq  = (float*)(w + off); off += (size_t)N_ * sizeof(float);
    off = (off + 255) & ~(size_t)255;
    float* accum = (float*)(w + off); off += 256;
    float* distbuf = (float*)(w + off);

    size_t avail = (ws_size > off) ? ws_size - off : 0;
    long maxrows = (long)(avail / ((size_t)V_ * sizeof(float)));
    int chunk = (maxrows >= N_) ? N_ : (int)maxrows;
    if (chunk < 1) chunk = 1;

    hipLaunchKernelGGL(init_accum, dim3(1), dim3(64), 0, stream, accum);
    hipLaunchKernelGGL(rowsq_kernel, dim3((V_ + 3)/4), dim3(256), 0, stream, CB, csq, V_);
    hipLaunchKernelGGL(transpose_kernel, dim3((T_ + 31)/32, C_/32, B_), dim3(32, 8), 0, stream, S, embT);
    hipLaunchKernelGGL(rowsq_kernel, dim3((N_ + 3)/4), dim3(256), 0, stream, embT, esq, N_);

    for (int row_lo = 0; row_lo < N_; row_lo += chunk){
        int row_hi = row_lo + chunk; if (row_hi > N_) row_hi = N_;
        int rows = row_hi - row_lo;
        hipLaunchKernelGGL(gemm_dist_kernel, dim3((rows + 127)/128, V_/128), dim3(256), 0, stream,
                           embT, CB, esq, csq, distbuf, row_lo, row_hi);
        hipLaunchKernelGGL(select_kernel, dim3(rows), dim3(256), 0, stream,
                           distbuf, codes, accum, row_lo);
    }
    hipLaunchKernelGGL(finalize_kernel, dim3(1), dim3(1), 0, stream, accum, out);
}

// Round 2
// 514.880 us; speedup vs baseline: 2.1485x; 2.1485x over previous
//
#include <hip/hip_runtime.h>
#include <hip/hip_bf16.h>
#include <cstdint>

#define B_ 8
#define C_ 512
#define T_ 1500
#define N_ (B_*T_)      // 12000 tokens
#define NPAD_ 12032     // 94*128
#define V_ 4096
#define K_ 100

typedef unsigned long long u64;
typedef __attribute__((ext_vector_type(8))) short short8;
typedef __attribute__((ext_vector_type(4))) float f32x4;

__device__ __forceinline__ unsigned short f2bf(float x){
    __hip_bfloat16 h = __float2bfloat16(x);
    return __builtin_bit_cast(unsigned short, h);
}

__device__ __forceinline__ void gll16(const unsigned short* g, unsigned short* l){
    __builtin_amdgcn_global_load_lds(
        (const __attribute__((address_space(1))) void*)g,
        (__attribute__((address_space(3))) void*)l, 16, 0, 0);
}

// ---------------- codebook: fp32 -> bf16 + csq (fp32-exact) ----------------
__global__ __launch_bounds__(256) void cbconv_kernel(const float* __restrict__ CB,
                                                     unsigned short* __restrict__ CBh,
                                                     float* __restrict__ csq){
    int wv = threadIdx.x >> 6, lane = threadIdx.x & 63;
    int r = blockIdx.x * 4 + wv;
    const float4* p4 = (const float4*)(CB + (size_t)r * C_);
    ushort4* o4 = (ushort4*)(CBh + (size_t)r * C_);
    float s = 0.f;
    #pragma unroll
    for (int j = 0; j < 2; ++j){
        float4 v = p4[lane + j*64];
        s += v.x*v.x + v.y*v.y + v.z*v.z + v.w*v.w;
        ushort4 h; h.x = f2bf(v.x); h.y = f2bf(v.y); h.z = f2bf(v.z); h.w = f2bf(v.w);
        o4[lane + j*64] = h;
    }
    #pragma unroll
    for (int o = 32; o; o >>= 1) s += __shfl_down(s, o, 64);
    if (lane == 0) csq[r] = s;
}

// ---------------- student: (B,C,T) fp32 -> embT bf16 (N,C) + esq partials ----------------
__global__ __launch_bounds__(256) void transpose_conv_kernel(const float* __restrict__ S,
                                                             unsigned short* __restrict__ embT,
                                                             float* __restrict__ esq){
    __shared__ float tile[32][33];
    __shared__ float psum[8][33];
    int b  = blockIdx.z;
    int c0 = blockIdx.y * 32;
    int t0 = blockIdx.x * 32;
    int tx = threadIdx.x, ty = threadIdx.y; // 32 x 8
    #pragma unroll
    for (int r = 0; r < 4; ++r){
        int c = c0 + ty + r*8;
        int t = t0 + tx;
        tile[ty + r*8][tx] = (t < T_) ? S[((size_t)b*C_ + c)*T_ + t] : 0.f;
    }
    __syncthreads();
    // esq partial: column tx (= token), sum over this block's 32 channels
    float ps = 0.f;
    #pragma unroll
    for (int r = 0; r < 4; ++r){ float v = tile[ty + r*8][tx]; ps += v * v; }
    psum[ty][tx] = ps;
    // transposed bf16 write
    #pragma unroll
    for (int r = 0; r < 4; ++r){
        int t = t0 + ty + r*8;
        int c = c0 + tx;
        if (t < T_) embT[((size_t)b*T_ + t)*C_ + c] = f2bf(tile[tx][ty + r*8]);
    }
    __syncthreads();
    if (ty == 0){
        int t = t0 + tx;
        if (t < T_){
            float s2 = 0.f;
            #pragma unroll
            for (int w = 0; w < 8; ++w) s2 += psum[w][tx];
            atomicAdd(&esq[b*T_ + t], s2);
        }
    }
}

// ---------------- bf16 MFMA GEMM: d2[n][v] = max(esq+csq-2*dot, 0) ----------------
// 128x128 tile, BK=32, 256 thr (4 waves, each 64x64 = 4x4 of 16x16x32)
__global__ __launch_bounds__(256) void gemm_d2_kernel(
    const unsigned short* __restrict__ A, const unsigned short* __restrict__ Bm,
    const float* __restrict__ esq, const float* __restrict__ csq,
    float* __restrict__ dist, int row_lo, int row_hi)
{
    __shared__ unsigned short As[128*32];
    __shared__ unsigned short Bs[128*32];
    int tid = threadIdx.x, lane = tid & 63, wv = tid >> 6;
    int row0 = row_lo + blockIdx.x * 128;
    int col0 = blockIdx.y * 128;

    // staging: each lane moves 16B; wave w covers rows [w*32, w*32+32) in two ops
    int sr = lane >> 2;            // 0..15
    int sk = (lane & 3) * 8;       // 0,8,16,24 (bf16 units)
    int ar0 = row0 + wv*32 + sr;       int ar1 = ar0 + 16;
    int ca0 = (ar0 < N_) ? ar0 : N_-1; int ca1 = (ar1 < N_) ? ar1 : N_-1;
    const unsigned short* Ap0 = A  + (size_t)ca0 * C_ + sk;
    const unsigned short* Ap1 = A  + (size_t)ca1 * C_ + sk;
    const unsigned short* Bp0 = Bm + (size_t)(col0 + wv*32 + sr) * C_ + sk;
    const unsigned short* Bp1 = Bp0 + (size_t)16 * C_;
    unsigned short* Ad0 = &As[(wv*32     ) * 32];
    unsigned short* Ad1 = &As[(wv*32 + 16) * 32];
    unsigned short* Bd0 = &Bs[(wv*32     ) * 32];
    unsigned short* Bd1 = &Bs[(wv*32 + 16) * 32];

    int wm = (wv >> 1) * 64, wn = (wv & 1) * 64;
    int fr = lane & 15;            // fragment row (m or n)
    int fk = (lane >> 4) * 8;      // fragment k offset

    f32x4 acc[4][4];
    #pragma unroll
    for (int i = 0; i < 4; ++i)
        #pragma unroll
        for (int j = 0; j < 4; ++j) acc[i][j] = (f32x4){0.f, 0.f, 0.f, 0.f};

    for (int kt = 0; kt < C_/32; ++kt){
        int k0 = kt * 32;
        gll16(Ap0 + k0, Ad0);
        gll16(Ap1 + k0, Ad1);
        gll16(Bp0 + k0, Bd0);
        gll16(Bp1 + k0, Bd1);
        __syncthreads();   // drains vmcnt: staged data visible
        short8 af[4], bf[4];
        #pragma unroll
        for (int i = 0; i < 4; ++i) af[i] = *(const short8*)&As[(wm + i*16 + fr)*32 + fk];
        #pragma unroll
        for (int j = 0; j < 4; ++j) bf[j] = *(const short8*)&Bs[(wn + j*16 + fr)*32 + fk];
        #pragma unroll
        for (int i = 0; i < 4; ++i)
            #pragma unroll
            for (int j = 0; j < 4; ++j)
                acc[i][j] = __builtin_amdgcn_mfma_f32_16x16x32_bf16(af[i], bf[j], acc[i][j], 0, 0, 0);
        __syncthreads();   // before overwriting the single LDS buffer
    }

    // epilogue: C/D layout col=lane&15, row=(lane>>4)*4+reg  [m89/m91 verified]
    int er = (lane >> 4) * 4;
    int ec = lane & 15;
    #pragma unroll
    for (int i = 0; i < 4; ++i){
        #pragma unroll
        for (int r = 0; r < 4; ++r){
            int n = row0 + wm + i*16 + er + r;
            if (n >= row_hi) continue;
            float en = esq[n];
            #pragma unroll
            for (int j = 0; j < 4; ++j){
                int v = col0 + wn + j*16 + ec;
                float d2 = en + csq[v] - 2.f * acc[i][j][r];
                dist[(size_t)(n - row_lo) * V_ + v] = fmaxf(d2, 0.f);
            }
        }
    }
}

// ---------------- selection: atomic-free binary search on d2 bits ----------------
__global__ __launch_bounds__(256) void select_kernel(const float* __restrict__ dist,
                                                     const int* __restrict__ codes,
                                                     float* __restrict__ accum, int row_lo){
    int n = row_lo + blockIdx.x;
    int tid = threadIdx.x, lane = tid & 63, wv = tid >> 6;
    const float* row = dist + (size_t)blockIdx.x * V_;

    float f[16]; unsigned u[16];
    const float4* r4 = (const float4*)row;
    #pragma unroll
    for (int i = 0; i < 4; ++i){
        float4 v = r4[tid + i*256];
        f[i*4+0] = v.x; f[i*4+1] = v.y; f[i*4+2] = v.z; f[i*4+3] = v.w;
    }
    #pragma unroll
    for (int i = 0; i < 16; ++i) u[i] = __float_as_uint(f[i]);

    // min 44-bit key (d2, idx) + max bits
    u64 kmin = ~0ull; unsigned umax = 0u;
    #pragma unroll
    for (int i = 0; i < 16; ++i){
        int idx = (tid + (i>>2)*256)*4 + (i&3);
        u64 key = ((u64)u[i] << 12) | (unsigned)idx;
        if (key < kmin) kmin = key;
        if (u[i] > umax) umax = u[i];
    }
    #pragma unroll
    for (int o = 32; o; o >>= 1){
        u64 ok = __shfl_down(kmin, o, 64); if (ok < kmin) kmin = ok;
        unsigned om = __shfl_down(umax, o, 64); if (om > umax) umax = om;
    }
    __shared__ u64 skey[4]; __shared__ unsigned smax[4];
    __shared__ int scnt[2][4];
    __shared__ float ssum[4]; __shared__ int scls[4];
    if (lane == 0){ skey[wv] = kmin; smax[wv] = umax; }
    __syncthreads();
    u64 gk = skey[0]; unsigned gmax = smax[0];
    #pragma unroll
    for (int w = 1; w < 4; ++w){
        if (skey[w] < gk) gk = skey[w];
        if (smax[w] > gmax) gmax = smax[w];
    }
    unsigned umin = (unsigned)(gk >> 12);
    int idx0 = (int)(gk & 0xFFFu);
    float d0 = sqrtf(__uint_as_float(umin));

    // binary search for t = 100th-smallest d2 bits (uint order == float order, all >= 0)
    unsigned P; int hb;
    unsigned diffb = umin ^ gmax;
    if (diffb == 0u){ P = umin; hb = -1; }
    else {
        hb = 31 - __clz((int)diffb);
        unsigned mask = (hb == 31) ? 0xFFFFFFFFu : ((1u << (hb+1)) - 1u);
        P = umin & ~mask;
    }
    int par = 0;
    for (int b = hb; b >= 0; --b){
        unsigned cand = P | (1u << b);
        int c = 0;
        #pragma unroll
        for (int i = 0; i < 16; ++i) c += (u[i] < cand) ? 1 : 0;
        #pragma unroll
        for (int o = 32; o; o >>= 1) c += __shfl_down(c, o, 64);
        if (lane == 0) scnt[par][wv] = c;
        __syncthreads();
        int tot = scnt[par][0] + scnt[par][1] + scnt[par][2] + scnt[par][3];
        if (tot <= K_-1) P = cand;   // invariant: count(<P) <= 99 < count(<P + 2^b)
        par ^= 1;
    }
    unsigned t = P;                  // exact rank-99 (0-indexed) d2 value
    float tval = sqrtf(__uint_as_float(t));

    // softmax denom over the top-100 (ties at t via multiplicity — loss-invariant)
    float s = 0.f; int cl = 0;
    #pragma unroll
    for (int i = 0; i < 16; ++i){
        if (u[i] < t){ s += __expf(d0 - sqrtf(f[i])); cl++; }
    }
    #pragma unroll
    for (int o = 32; o; o >>= 1){ s += __shfl_down(s, o, 64); cl += __shfl_down(cl, o, 64); }
    if (lane == 0){ ssum[wv] = s; scls[wv] = cl; }
    __syncthreads();
    if (tid == 0){
        float S = ssum[0]+ssum[1]+ssum[2]+ssum[3];
        int cls = scls[0]+scls[1]+scls[2]+scls[3];
        S += (float)(K_ - cls) * __expf(d0 - tval);
        int code = codes[n];
        unsigned ucode = __float_as_uint(row[code]);
        float dcode = sqrtf(__uint_as_float(ucode));
        if (ucode > t) S += __expf(d0 - dcode) - __expf(d0 - tval); // include_correct swap
        float nll = dcode - d0 + __logf(S);
        atomicAdd(&accum[0], nll);
        atomicAdd(&accum[1], (idx0 == code) ? 1.f : 0.f);
    }
}

__global__ void finalize_kernel(const float* __restrict__ accum, float* __restrict__ out){
    float loss = accum[0] / (float)N_;
    float acc  = accum[1] / (float)N_;
    out[0] = loss;
    out[1] = acc;   // local prediction is always candidate 0 -> == global accuracy
    out[2] = acc;
    out[3] = 1.0f;  // include_correct guarantees membership exactly
}

// ---------------- launcher ----------------
extern "C" void kernel_launch(void* const* d_in, const int* in_sizes, int n_in,
                              void* d_out, int out_size, void* d_ws, size_t ws_size,
                              hipStream_t stream){
    const float* S   = (const float*)d_in[0];
    const int* codes = (const int*)d_in[1];
    const float* CB  = (const float*)d_in[2];
    float* out = (float*)d_out;

    char* w = (char*)d_ws;
    size_t off = 0;
    unsigned short* embT = (unsigned short*)(w + off); off += (size_t)NPAD_ * C_ * 2;
    unsigned short* CBh  = (unsigned short*)(w + off); off += (size_t)V_ * C_ * 2;
    float* csq = (float*)(w + off); off += (size_t)V_ * 4;
    float* esq = (float*)(w + off); off += (size_t)N_ * 4;
    off = (off + 255) & ~(size_t)255;
    float* accum = (float*)(w + off); off += 256;
    float* distbuf = (float*)(w + off);

    size_t avail = (ws_size > off) ? ws_size - off : 0;
    long maxrows = (long)(avail / ((size_t)V_ * 4));
    int chunk = (maxrows >= N_) ? N_ : (int)maxrows;
    if (chunk < 1) chunk = 1;

    hipMemsetAsync(esq, 0, (size_t)N_ * 4, stream);
    hipMemsetAsync(accum, 0, 8, stream);
    hipLaunchKernelGGL(cbconv_kernel, dim3(V_/4), dim3(256), 0, stream, CB, CBh, csq);
    hipLaunchKernelGGL(transpose_conv_kernel, dim3((T_+31)/32, C_/32, B_), dim3(32, 8), 0, stream,
                       S, embT, esq);

    for (int row_lo = 0; row_lo < N_; row_lo += chunk){
        int row_hi = row_lo + chunk; if (row_hi > N_) row_hi = N_;
        int rows = row_hi - row_lo;
        hipLaunchKernelGGL(gemm_d2_kernel, dim3((rows + 127)/128, V_/128), dim3(256), 0, stream,
                           embT, CBh, esq, csq, distbuf, row_lo, row_hi);
        hipLaunchKernelGGL(select_kernel, dim3(rows), dim3(256), 0, stream,
                           distbuf, codes, accum, row_lo);
    }
    hipLaunchKernelGGL(finalize_kernel, dim3(1), dim3(1), 0, stream, accum, out);
}

// Round 3
// 499.283 us; speedup vs baseline: 2.2157x; 1.0312x over previous
//
#include <hip/hip_runtime.h>
#include <hip/hip_bf16.h>
#include <cstdint>

#define B_ 8
#define C_ 512
#define T_ 1500
#define N_ (B_*T_)      // 12000 tokens
#define NPAD_ 12032     // 94*128
#define V_ 4096
#define K_ 100
#define CAP_ 512

typedef unsigned long long u64;
typedef __attribute__((ext_vector_type(8))) short short8;
typedef __attribute__((ext_vector_type(4))) float f32x4;

__device__ __forceinline__ unsigned short f2bf(float x){
    __hip_bfloat16 h = __float2bfloat16(x);
    return __builtin_bit_cast(unsigned short, h);
}

__device__ __forceinline__ void gll16(const unsigned short* g, unsigned short* l){
    __builtin_amdgcn_global_load_lds(
        (const __attribute__((address_space(1))) void*)g,
        (__attribute__((address_space(3))) void*)l, 16, 0, 0);
}

// ---------------- codebook: fp32 -> bf16 + csq (fp32-exact) ----------------
__global__ __launch_bounds__(256) void cbconv_kernel(const float* __restrict__ CB,
                                                     unsigned short* __restrict__ CBh,
                                                     float* __restrict__ csq){
    int wv = threadIdx.x >> 6, lane = threadIdx.x & 63;
    int r = blockIdx.x * 4 + wv;
    const float4* p4 = (const float4*)(CB + (size_t)r * C_);
    ushort4* o4 = (ushort4*)(CBh + (size_t)r * C_);
    float s = 0.f;
    #pragma unroll
    for (int j = 0; j < 2; ++j){
        float4 v = p4[lane + j*64];
        s += v.x*v.x + v.y*v.y + v.z*v.z + v.w*v.w;
        ushort4 h; h.x = f2bf(v.x); h.y = f2bf(v.y); h.z = f2bf(v.z); h.w = f2bf(v.w);
        o4[lane + j*64] = h;
    }
    #pragma unroll
    for (int o = 32; o; o >>= 1) s += __shfl_down(s, o, 64);
    if (lane == 0) csq[r] = s;
}

// ---------------- student: (B,C,T) fp32 -> embT bf16 (N,C) + esq partials ----------------
__global__ __launch_bounds__(256) void transpose_conv_kernel(const float* __restrict__ S,
                                                             unsigned short* __restrict__ embT,
                                                             float* __restrict__ esq){
    __shared__ float tile[32][33];
    __shared__ float psum[8][33];
    int b  = blockIdx.z;
    int c0 = blockIdx.y * 32;
    int t0 = blockIdx.x * 32;
    int tx = threadIdx.x, ty = threadIdx.y; // 32 x 8
    #pragma unroll
    for (int r = 0; r < 4; ++r){
        int c = c0 + ty + r*8;
        int t = t0 + tx;
        tile[ty + r*8][tx] = (t < T_) ? S[((size_t)b*C_ + c)*T_ + t] : 0.f;
    }
    __syncthreads();
    float ps = 0.f;
    #pragma unroll
    for (int r = 0; r < 4; ++r){ float v = tile[ty + r*8][tx]; ps += v * v; }
    psum[ty][tx] = ps;
    #pragma unroll
    for (int r = 0; r < 4; ++r){
        int t = t0 + ty + r*8;
        int c = c0 + tx;
        if (t < T_) embT[((size_t)b*T_ + t)*C_ + c] = f2bf(tile[tx][ty + r*8]);
    }
    __syncthreads();
    if (ty == 0){
        int t = t0 + tx;
        if (t < T_){
            float s2 = 0.f;
            #pragma unroll
            for (int w = 0; w < 8; ++w) s2 += psum[w][tx];
            atomicAdd(&esq[b*T_ + t], s2);
        }
    }
}

// ---------------- bf16 MFMA GEMM: d2[n][v] = max(esq+csq-2*dot, 0) ----------------
__global__ __launch_bounds__(256) void gemm_d2_kernel(
    const unsigned short* __restrict__ A, const unsigned short* __restrict__ Bm,
    const float* __restrict__ esq, const float* __restrict__ csq,
    float* __restrict__ dist, int row_lo, int row_hi)
{
    __shared__ unsigned short As[128*32];
    __shared__ unsigned short Bs[128*32];
    int tid = threadIdx.x, lane = tid & 63, wv = tid >> 6;
    int row0 = row_lo + blockIdx.x * 128;
    int col0 = blockIdx.y * 128;

    int sr = lane >> 2;
    int sk = (lane & 3) * 8;
    int ar0 = row0 + wv*32 + sr;       int ar1 = ar0 + 16;
    int ca0 = (ar0 < N_) ? ar0 : N_-1; int ca1 = (ar1 < N_) ? ar1 : N_-1;
    const unsigned short* Ap0 = A  + (size_t)ca0 * C_ + sk;
    const unsigned short* Ap1 = A  + (size_t)ca1 * C_ + sk;
    const unsigned short* Bp0 = Bm + (size_t)(col0 + wv*32 + sr) * C_ + sk;
    const unsigned short* Bp1 = Bp0 + (size_t)16 * C_;
    unsigned short* Ad0 = &As[(wv*32     ) * 32];
    unsigned short* Ad1 = &As[(wv*32 + 16) * 32];
    unsigned short* Bd0 = &Bs[(wv*32     ) * 32];
    unsigned short* Bd1 = &Bs[(wv*32 + 16) * 32];

    int wm = (wv >> 1) * 64, wn = (wv & 1) * 64;
    int fr = lane & 15;
    int fk = (lane >> 4) * 8;

    f32x4 acc[4][4];
    #pragma unroll
    for (int i = 0; i < 4; ++i)
        #pragma unroll
        for (int j = 0; j < 4; ++j) acc[i][j] = (f32x4){0.f, 0.f, 0.f, 0.f};

    for (int kt = 0; kt < C_/32; ++kt){
        int k0 = kt * 32;
        gll16(Ap0 + k0, Ad0);
        gll16(Ap1 + k0, Ad1);
        gll16(Bp0 + k0, Bd0);
        gll16(Bp1 + k0, Bd1);
        __syncthreads();
        short8 af[4], bf[4];
        #pragma unroll
        for (int i = 0; i < 4; ++i) af[i] = *(const short8*)&As[(wm + i*16 + fr)*32 + fk];
        #pragma unroll
        for (int j = 0; j < 4; ++j) bf[j] = *(const short8*)&Bs[(wn + j*16 + fr)*32 + fk];
        #pragma unroll
        for (int i = 0; i < 4; ++i)
            #pragma unroll
            for (int j = 0; j < 4; ++j)
                acc[i][j] = __builtin_amdgcn_mfma_f32_16x16x32_bf16(af[i], bf[j], acc[i][j], 0, 0, 0);
        __syncthreads();
    }

    int er = (lane >> 4) * 4;
    int ec = lane & 15;
    #pragma unroll
    for (int i = 0; i < 4; ++i){
        #pragma unroll
        for (int r = 0; r < 4; ++r){
            int n = row0 + wm + i*16 + er + r;
            if (n >= row_hi) continue;
            float en = esq[n];
            #pragma unroll
            for (int j = 0; j < 4; ++j){
                int v = col0 + wn + j*16 + ec;
                float d2 = en + csq[v] - 2.f * acc[i][j][r];
                dist[(size_t)(n - row_lo) * V_ + v] = fmaxf(d2, 0.f);
            }
        }
    }
}

// ---------------- selection v2: histogram select (1 count pass, ~7 barriers) ----------------
__global__ __launch_bounds__(256) void select_kernel(const float* __restrict__ dist,
                                                     const int* __restrict__ codes,
                                                     float* __restrict__ accum, int row_lo){
    int n = row_lo + blockIdx.x;
    int tid = threadIdx.x, lane = tid & 63, wv = tid >> 6;
    const float* row = dist + (size_t)blockIdx.x * V_;

    float f[16]; unsigned u[16];
    const float4* r4 = (const float4*)row;
    #pragma unroll
    for (int i = 0; i < 4; ++i){
        float4 v = r4[tid + i*256];
        f[i*4+0] = v.x; f[i*4+1] = v.y; f[i*4+2] = v.z; f[i*4+3] = v.w;
    }
    #pragma unroll
    for (int i = 0; i < 16; ++i) u[i] = __float_as_uint(f[i]);

    __shared__ u64 skey[4]; __shared__ unsigned smax[4];
    __shared__ int hist[256];
    __shared__ unsigned coll[CAP_];
    __shared__ int sBk, sBase, sCnt;
    __shared__ unsigned sT;
    __shared__ int scnt2[2][4];
    __shared__ float ssum[4]; __shared__ int scls[4];

    // ---- block min-key / max ----
    u64 kmin = ~0ull; unsigned umax = 0u;
    #pragma unroll
    for (int i = 0; i < 16; ++i){
        int idx = (tid + (i>>2)*256)*4 + (i&3);
        u64 key = ((u64)u[i] << 12) | (unsigned)idx;
        if (key < kmin) kmin = key;
        if (u[i] > umax) umax = u[i];
    }
    #pragma unroll
    for (int o = 32; o; o >>= 1){
        u64 ok = __shfl_down(kmin, o, 64); if (ok < kmin) kmin = ok;
        unsigned om = __shfl_down(umax, o, 64); if (om > umax) umax = om;
    }
    if (lane == 0){ skey[wv] = kmin; smax[wv] = umax; }
    hist[tid] = 0;   // also serves as the pre-histogram zeroing
    __syncthreads();                                              // B1
    u64 gk = skey[0]; unsigned gmax = smax[0];
    #pragma unroll
    for (int w = 1; w < 4; ++w){
        if (skey[w] < gk) gk = skey[w];
        if (smax[w] > gmax) gmax = smax[w];
    }
    unsigned umin = (unsigned)(gk >> 12);
    int idx0 = (int)(gk & 0xFFFu);
    float d0 = sqrtf(__uint_as_float(umin));

    unsigned t;
    if (umin == gmax){
        t = umin;                     // degenerate: all equal
        __syncthreads();              // keep barrier structure trivially uniform
    } else {
        // ---- 256-bin linear histogram (monotone binning) ----
        float fmn = __uint_as_float(umin), fmx = __uint_as_float(gmax);
        float invw = 256.0f / (fmx - fmn);
        int bin[16];
        #pragma unroll
        for (int i = 0; i < 16; ++i){
            int bb = (int)((f[i] - fmn) * invw);
            bin[i] = (bb > 255) ? 255 : bb;
            atomicAdd(&hist[bin[i]], 1);
        }
        __syncthreads();                                          // B2
        // ---- wave 0: scan 256 bins, locate rank-99 bin ----
        if (wv == 0){
            int h0 = hist[4*lane], h1 = hist[4*lane+1], h2 = hist[4*lane+2], h3 = hist[4*lane+3];
            int lsum = h0 + h1 + h2 + h3;
            int inc = lsum;
            #pragma unroll
            for (int o = 1; o < 64; o <<= 1){
                int y = __shfl_up(inc, o, 64);
                if (lane >= o) inc += y;
            }
            int ex = inc - lsum;   // exclusive before this lane's 4 bins
            int e0 = ex, e1 = e0 + h0, e2 = e1 + h1, e3 = e2 + h2;
            if (e0 <= K_-1 && K_-1 < e0 + h0){ sBk = 4*lane;   sBase = e0; sCnt = h0; }
            if (e1 <= K_-1 && K_-1 < e1 + h1){ sBk = 4*lane+1; sBase = e1; sCnt = h1; }
            if (e2 <= K_-1 && K_-1 < e2 + h2){ sBk = 4*lane+2; sBase = e2; sCnt = h2; }
            if (e3 <= K_-1 && K_-1 < e3 + h3){ sBk = 4*lane+3; sBase = e3; sCnt = h3; }
            if (lane == 0) hist[0] = 0;  // reuse hist[0] as collect counter... no: use sCnt copy
        }
        __syncthreads();                                          // B3
        int Bk = sBk, base = sBase, bcnt = sCnt;
        int rk = K_ - 1 - base;       // rank within the bin
        if (bcnt <= CAP_){
            if (tid == 0) sBase = 0;  // reuse sBase as collect counter
            __syncthreads();                                      // B4
            #pragma unroll
            for (int i = 0; i < 16; ++i){
                if (bin[i] == Bk){
                    int pos = atomicAdd(&sBase, 1);
                    coll[pos] = u[i];
                }
            }
            __syncthreads();                                      // B5
            if (wv == 0){
                int m = sBase;
                unsigned v0[CAP_/64];
                unsigned lmn = 0xFFFFFFFFu, lmx = 0u;
                #pragma unroll
                for (int j = 0; j < CAP_/64; ++j){
                    int p = lane + j*64;
                    unsigned val = (p < m) ? coll[p] : 0xFFFFFFFFu;
                    v0[j] = val;
                    if (val != 0xFFFFFFFFu){ if (val < lmn) lmn = val; if (val > lmx) lmx = val; }
                }
                #pragma unroll
                for (int o = 32; o; o >>= 1){
                    unsigned a = __shfl_xor(lmn, o, 64); if (a < lmn) lmn = a;
                    unsigned b = __shfl_xor(lmx, o, 64); if (b > lmx) lmx = b;
                }
                unsigned P;
                unsigned diff = lmn ^ lmx;
                if (diff == 0u) P = lmn;
                else {
                    int hb = 31 - __clz((int)diff);
                    unsigned mask = (hb == 31) ? 0xFFFFFFFFu : ((1u << (hb+1)) - 1u);
                    P = lmn & ~mask;
                    for (int b = hb; b >= 0; --b){
                        unsigned cand = P | (1u << b);
                        int c = 0;
                        #pragma unroll
                        for (int j = 0; j < CAP_/64; ++j) c += (v0[j] < cand) ? 1 : 0;
                        #pragma unroll
                        for (int o = 32; o; o >>= 1) c += __shfl_xor(c, o, 64);
                        if (c <= rk) P = cand;
                    }
                }
                if (lane == 0) sT = P;
            }
            __syncthreads();                                      // B6
            t = sT;
        } else {
            // ---- fallback: block-wide bitwise search (rare) ----
            unsigned P;
            unsigned diffb = umin ^ gmax;
            int hb = 31 - __clz((int)diffb);
            unsigned mask = (hb == 31) ? 0xFFFFFFFFu : ((1u << (hb+1)) - 1u);
            P = umin & ~mask;
            int par = 0;
            for (int b = hb; b >= 0; --b){
                unsigned cand = P | (1u << b);
                int c = 0;
                #pragma unroll
                for (int i = 0; i < 16; ++i) c += (u[i] < cand) ? 1 : 0;
                #pragma unroll
                for (int o = 32; o; o >>= 1) c += __shfl_down(c, o, 64);
                if (lane == 0) scnt2[par][wv] = c;
                __syncthreads();
                int tot = scnt2[par][0] + scnt2[par][1] + scnt2[par][2] + scnt2[par][3];
                if (tot <= K_-1) P = cand;
                par ^= 1;
            }
            t = P;
        }
    }
    float tval = sqrtf(__uint_as_float(t));

    // ---- softmax denom over the top-100 (tie multiplicity at t) ----
    float s = 0.f; int cl = 0;
    #pragma unroll
    for (int i = 0; i < 16; ++i){
        if (u[i] < t){ s += __expf(d0 - sqrtf(f[i])); cl++; }
    }
    #pragma unroll
    for (int o = 32; o; o >>= 1){ s += __shfl_down(s, o, 64); cl += __shfl_down(cl, o, 64); }
    if (lane == 0){ ssum[wv] = s; scls[wv] = cl; }
    __syncthreads();                                              // B7
    if (tid == 0){
        float S = ssum[0]+ssum[1]+ssum[2]+ssum[3];
        int cls = scls[0]+scls[1]+scls[2]+scls[3];
        S += (float)(K_ - cls) * __expf(d0 - tval);
        int code = codes[n];
        unsigned ucode = __float_as_uint(row[code]);
        float dcode = sqrtf(__uint_as_float(ucode));
        if (ucode > t) S += __expf(d0 - dcode) - __expf(d0 - tval);
        float nll = dcode - d0 + __logf(S);
        atomicAdd(&accum[0], nll);
        atomicAdd(&accum[1], (idx0 == code) ? 1.f : 0.f);
    }
}

__global__ void finalize_kernel(const float* __restrict__ accum, float* __restrict__ out){
    float loss = accum[0] / (float)N_;
    float acc  = accum[1] / (float)N_;
    out[0] = loss;
    out[1] = acc;
    out[2] = acc;
    out[3] = 1.0f;
}

// ---------------- launcher ----------------
extern "C" void kernel_launch(void* const* d_in, const int* in_sizes, int n_in,
                              void* d_out, int out_size, void* d_ws, size_t ws_size,
                              hipStream_t stream){
    const float* S   = (const float*)d_in[0];
    const int* codes = (const int*)d_in[1];
    const float* CB  = (const float*)d_in[2];
    float* out = (float*)d_out;

    char* w = (char*)d_ws;
    size_t off = 0;
    unsigned short* embT = (unsigned short*)(w + off); off += (size_t)NPAD_ * C_ * 2;
    unsigned short* CBh  = (unsigned short*)(w + off); off += (size_t)V_ * C_ * 2;
    float* csq = (float*)(w + off); off += (size_t)V_ * 4;
    float* esq = (float*)(w + off); off += (size_t)N_ * 4;
    off = (off + 255) & ~(size_t)255;
    float* accum = (float*)(w + off); off += 256;
    float* distbuf = (float*)(w + off);

    size_t avail = (ws_size > off) ? ws_size - off : 0;
    long maxrows = (long)(avail / ((size_t)V_ * 4));
    int chunk = (maxrows >= N_) ? N_ : (int)maxrows;
    if (chunk < 1) chunk = 1;

    hipMemsetAsync(esq, 0, (size_t)N_ * 4, stream);
    hipMemsetAsync(accum, 0, 8, stream);
    hipLaunchKernelGGL(cbconv_kernel, dim3(V_/4), dim3(256), 0, stream, CB, CBh, csq);
    hipLaunchKernelGGL(transpose_conv_kernel, dim3((T_+31)/32, C_/32, B_), dim3(32, 8), 0, stream,
                       S, embT, esq);

    for (int row_lo = 0; row_lo < N_; row_lo += chunk){
        int row_hi = row_lo + chunk; if (row_hi > N_) row_hi = N_;
        int rows = row_hi - row_lo;
        hipLaunchKernelGGL(gemm_d2_kernel, dim3((rows + 127)/128, V_/128), dim3(256), 0, stream,
                           embT, CBh, esq, csq, distbuf, row_lo, row_hi);
        hipLaunchKernelGGL(select_kernel, dim3(rows), dim3(256), 0, stream,
                           distbuf, codes, accum, row_lo);
    }
    hipLaunchKernelGGL(finalize_kernel, dim3(1), dim3(1), 0, stream, accum, out);
}

// Round 4
// 280.171 us; speedup vs baseline: 3.9484x; 1.7821x over previous
//
#include <hip/hip_runtime.h>
#include <hip/hip_bf16.h>
#include <cstdint>

#define B_ 8
#define C_ 512
#define T_ 1500
#define N_ (B_*T_)      // 12000 tokens
#define NPAD_ 12032     // 94*128
#define V_ 4096
#define K_ 100

typedef unsigned long long u64;
typedef __attribute__((ext_vector_type(8))) short short8;
typedef __attribute__((ext_vector_type(4))) float f32x4;

__device__ __forceinline__ unsigned short f2bf(float x){
    __hip_bfloat16 h = __float2bfloat16(x);
    return __builtin_bit_cast(unsigned short, h);
}

__device__ __forceinline__ void gll16(const unsigned short* g, unsigned short* l){
    __builtin_amdgcn_global_load_lds(
        (const __attribute__((address_space(1))) void*)g,
        (__attribute__((address_space(3))) void*)l, 16, 0, 0);
}

// ---------------- codebook: fp32 -> bf16 + csq (fp32-exact) ----------------
__global__ __launch_bounds__(256) void cbconv_kernel(const float* __restrict__ CB,
                                                     unsigned short* __restrict__ CBh,
                                                     float* __restrict__ csq){
    int wv = threadIdx.x >> 6, lane = threadIdx.x & 63;
    int r = blockIdx.x * 4 + wv;
    const float4* p4 = (const float4*)(CB + (size_t)r * C_);
    ushort4* o4 = (ushort4*)(CBh + (size_t)r * C_);
    float s = 0.f;
    #pragma unroll
    for (int j = 0; j < 2; ++j){
        float4 v = p4[lane + j*64];
        s += v.x*v.x + v.y*v.y + v.z*v.z + v.w*v.w;
        ushort4 h; h.x = f2bf(v.x); h.y = f2bf(v.y); h.z = f2bf(v.z); h.w = f2bf(v.w);
        o4[lane + j*64] = h;
    }
    #pragma unroll
    for (int o = 32; o; o >>= 1) s += __shfl_down(s, o, 64);
    if (lane == 0) csq[r] = s;
}

// ---------------- student: (B,C,T) fp32 -> embT bf16 (N,C) + esq partials ----------------
__global__ __launch_bounds__(256) void transpose_conv_kernel(const float* __restrict__ S,
                                                             unsigned short* __restrict__ embT,
                                                             float* __restrict__ esq){
    __shared__ float tile[32][33];
    __shared__ float psum[8][33];
    int b  = blockIdx.z;
    int c0 = blockIdx.y * 32;
    int t0 = blockIdx.x * 32;
    int tx = threadIdx.x, ty = threadIdx.y; // 32 x 8
    #pragma unroll
    for (int r = 0; r < 4; ++r){
        int c = c0 + ty + r*8;
        int t = t0 + tx;
        tile[ty + r*8][tx] = (t < T_) ? S[((size_t)b*C_ + c)*T_ + t] : 0.f;
    }
    __syncthreads();
    float ps = 0.f;
    #pragma unroll
    for (int r = 0; r < 4; ++r){ float v = tile[ty + r*8][tx]; ps += v * v; }
    psum[ty][tx] = ps;
    #pragma unroll
    for (int r = 0; r < 4; ++r){
        int t = t0 + ty + r*8;
        int c = c0 + tx;
        if (t < T_) embT[((size_t)b*T_ + t)*C_ + c] = f2bf(tile[tx][ty + r*8]);
    }
    __syncthreads();
    if (ty == 0){
        int t = t0 + tx;
        if (t < T_){
            float s2 = 0.f;
            #pragma unroll
            for (int w = 0; w < 8; ++w) s2 += psum[w][tx];
            atomicAdd(&esq[b*T_ + t], s2);
        }
    }
}

// ---------------- bf16 MFMA GEMM: d2[n][v] = max(esq+csq-2*dot, 0) ----------------
__global__ __launch_bounds__(256) void gemm_d2_kernel(
    const unsigned short* __restrict__ A, const unsigned short* __restrict__ Bm,
    const float* __restrict__ esq, const float* __restrict__ csq,
    float* __restrict__ dist, int row_lo, int row_hi)
{
    __shared__ unsigned short As[128*32];
    __shared__ unsigned short Bs[128*32];
    int tid = threadIdx.x, lane = tid & 63, wv = tid >> 6;
    int row0 = row_lo + blockIdx.x * 128;
    int col0 = blockIdx.y * 128;

    int sr = lane >> 2;
    int sk = (lane & 3) * 8;
    int ar0 = row0 + wv*32 + sr;       int ar1 = ar0 + 16;
    int ca0 = (ar0 < N_) ? ar0 : N_-1; int ca1 = (ar1 < N_) ? ar1 : N_-1;
    const unsigned short* Ap0 = A  + (size_t)ca0 * C_ + sk;
    const unsigned short* Ap1 = A  + (size_t)ca1 * C_ + sk;
    const unsigned short* Bp0 = Bm + (size_t)(col0 + wv*32 + sr) * C_ + sk;
    const unsigned short* Bp1 = Bp0 + (size_t)16 * C_;
    unsigned short* Ad0 = &As[(wv*32     ) * 32];
    unsigned short* Ad1 = &As[(wv*32 + 16) * 32];
    unsigned short* Bd0 = &Bs[(wv*32     ) * 32];
    unsigned short* Bd1 = &Bs[(wv*32 + 16) * 32];

    int wm = (wv >> 1) * 64, wn = (wv & 1) * 64;
    int fr = lane & 15;
    int fk = (lane >> 4) * 8;

    f32x4 acc[4][4];
    #pragma unroll
    for (int i = 0; i < 4; ++i)
        #pragma unroll
        for (int j = 0; j < 4; ++j) acc[i][j] = (f32x4){0.f, 0.f, 0.f, 0.f};

    for (int kt = 0; kt < C_/32; ++kt){
        int k0 = kt * 32;
        gll16(Ap0 + k0, Ad0);
        gll16(Ap1 + k0, Ad1);
        gll16(Bp0 + k0, Bd0);
        gll16(Bp1 + k0, Bd1);
        __syncthreads();
        short8 af[4], bf[4];
        #pragma unroll
        for (int i = 0; i < 4; ++i) af[i] = *(const short8*)&As[(wm + i*16 + fr)*32 + fk];
        #pragma unroll
        for (int j = 0; j < 4; ++j) bf[j] = *(const short8*)&Bs[(wn + j*16 + fr)*32 + fk];
        #pragma unroll
        for (int i = 0; i < 4; ++i)
            #pragma unroll
            for (int j = 0; j < 4; ++j)
                acc[i][j] = __builtin_amdgcn_mfma_f32_16x16x32_bf16(af[i], bf[j], acc[i][j], 0, 0, 0);
        __syncthreads();
    }

    int er = (lane >> 4) * 4;
    int ec = lane & 15;
    #pragma unroll
    for (int i = 0; i < 4; ++i){
        #pragma unroll
        for (int r = 0; r < 4; ++r){
            int n = row0 + wm + i*16 + er + r;
            if (n >= row_hi) continue;
            float en = esq[n];
            #pragma unroll
            for (int j = 0; j < 4; ++j){
                int v = col0 + wn + j*16 + ec;
                float d2 = en + csq[v] - 2.f * acc[i][j][r];
                dist[(size_t)(n - row_lo) * V_ + v] = fmaxf(d2, 0.f);
            }
        }
    }
}

// ---------------- selection v3: one wave per row, no barriers, no global atomics ----------------
__global__ __launch_bounds__(256, 4) void select_kernel(const float* __restrict__ dist,
                                                        const int* __restrict__ codes,
                                                        float2* __restrict__ pairbuf,
                                                        int row_lo, int nrows){
    int tid = threadIdx.x, lane = tid & 63, wv = tid >> 6;
    int lrow = blockIdx.x * 4 + wv;
    if (lrow >= nrows) return;               // wave-uniform, no barriers below
    int n = row_lo + lrow;
    const float* row = dist + (size_t)lrow * V_;

    __shared__ unsigned hist[4][256] __attribute__((aligned(16)));
    __shared__ unsigned coll[4][64];
    __shared__ unsigned collcnt[4];

    // ---- load 64 values/lane, coalesced; issue all 16 loads + code dist early ----
    const float4* r4 = (const float4*)row;
    float4 vv[16];
    #pragma unroll
    for (int j = 0; j < 16; ++j) vv[j] = r4[lane + j*64];
    int code = codes[n];
    unsigned ucode = __float_as_uint(row[code]);   // broadcast load

    unsigned u[64];
    #pragma unroll
    for (int j = 0; j < 16; ++j){
        u[4*j+0] = __float_as_uint(vv[j].x);
        u[4*j+1] = __float_as_uint(vv[j].y);
        u[4*j+2] = __float_as_uint(vv[j].z);
        u[4*j+3] = __float_as_uint(vv[j].w);
    }

    // ---- min/max (uint order == float order, all >= 0) ----
    unsigned umin = u[0], umax = u[0];
    #pragma unroll
    for (int k = 1; k < 64; ++k){
        umin = (u[k] < umin) ? u[k] : umin;
        umax = (u[k] > umax) ? u[k] : umax;
    }
    #pragma unroll
    for (int o = 32; o; o >>= 1){
        unsigned a = (unsigned)__shfl_xor((int)umin, o, 64); if (a < umin) umin = a;
        unsigned b = (unsigned)__shfl_xor((int)umax, o, 64); if (b > umax) umax = b;
    }
    // ---- argmin (lowest index among value==umin) ----
    unsigned im = 0xFFFFFFFFu;
    #pragma unroll
    for (int k = 0; k < 64; ++k){
        unsigned idx = 4u*(unsigned)lane + (unsigned)((k >> 2)*256 + (k & 3));
        if (u[k] == umin && idx < im) im = idx;
    }
    #pragma unroll
    for (int o = 32; o; o >>= 1){
        unsigned a = (unsigned)__shfl_xor((int)im, o, 64); if (a < im) im = a;
    }
    int idx0 = (int)im;
    float d0 = sqrtf(__uint_as_float(umin));

    // ---- rank-99 threshold t via per-wave histogram + in-bin bitwise search ----
    unsigned t;
    if (umin == umax){
        t = umin;
    } else {
        ((uint4*)&hist[wv][0])[lane] = (uint4){0u,0u,0u,0u};
        if (lane == 0) collcnt[wv] = 0u;
        asm volatile("s_waitcnt lgkmcnt(0)" ::: "memory");
        float fmn = __uint_as_float(umin), fmx = __uint_as_float(umax);
        float invw = 256.0f / (fmx - fmn);
        #pragma unroll
        for (int k = 0; k < 64; ++k){
            float fk = __uint_as_float(u[k]);
            int b = (int)((fk - fmn) * invw); b = (b > 255) ? 255 : b;
            atomicAdd(&hist[wv][b], 1u);
        }
        asm volatile("s_waitcnt lgkmcnt(0)" ::: "memory");
        uint4 hq = ((uint4*)&hist[wv][0])[lane];
        unsigned lsum = hq.x + hq.y + hq.z + hq.w;
        unsigned inc = lsum;
        #pragma unroll
        for (int o = 1; o < 64; o <<= 1){
            unsigned y = (unsigned)__shfl_up((int)inc, o, 64);
            if (lane >= o) inc += y;
        }
        unsigned e0 = inc - lsum;
        unsigned e1 = e0 + hq.x, e2 = e1 + hq.y, e3 = e2 + hq.z, e4 = e3 + hq.w;
        int sel = -1;
        if      (e0 <= 99u && 99u < e1) sel = 0;
        else if (e1 <= 99u && 99u < e2) sel = 1;
        else if (e2 <= 99u && 99u < e3) sel = 2;
        else if (e3 <= 99u && 99u < e4) sel = 3;
        u64 bal = __ballot(sel >= 0);
        int src = __ffsll(bal) - 1;
        unsigned myBk = (unsigned)(4*lane + (sel < 0 ? 0 : sel));
        unsigned myBase = (sel == 1) ? e1 : (sel == 2) ? e2 : (sel == 3) ? e3 : e0;
        int Bk   = __shfl((int)myBk,   src, 64);
        int base = __shfl((int)myBase, src, 64);
        int rk = 99 - base;
        // collect members of bin Bk (cap 64; overflow -> full fallback)
        #pragma unroll
        for (int k = 0; k < 64; ++k){
            float fk = __uint_as_float(u[k]);
            int b = (int)((fk - fmn) * invw); b = (b > 255) ? 255 : b;
            if (b == Bk){
                unsigned pos = atomicAdd(&collcnt[wv], 1u);
                if (pos < 64u) coll[wv][pos] = u[k];
            }
        }
        asm volatile("s_waitcnt lgkmcnt(0)" ::: "memory");
        unsigned bcnt = collcnt[wv];
        if (bcnt <= 64u){
            unsigned w = (lane < (int)bcnt) ? coll[wv][lane] : 0xFFFFFFFFu;
            unsigned wmn = (lane < (int)bcnt) ? w : 0xFFFFFFFFu;
            unsigned wmx = (lane < (int)bcnt) ? w : 0u;
            #pragma unroll
            for (int o = 32; o; o >>= 1){
                unsigned a = (unsigned)__shfl_xor((int)wmn, o, 64); if (a < wmn) wmn = a;
                unsigned b = (unsigned)__shfl_xor((int)wmx, o, 64); if (b > wmx) wmx = b;
            }
            unsigned P;
            if (wmn == wmx) P = wmn;
            else {
                int hb = 31 - __clz((int)(wmn ^ wmx));
                unsigned mask = (hb == 31) ? 0xFFFFFFFFu : ((1u << (hb+1)) - 1u);
                P = wmn & ~mask;
                for (int b = hb; b >= 0; --b){
                    unsigned cand = P | (1u << b);
                    int c = __popcll(__ballot(w < cand));
                    if (c <= rk) P = cand;       // count(<P) stays <= rk invariant
                }
            }
            t = P;
        } else {
            // rare fallback: full-range bitwise search over register data
            int hb = 31 - __clz((int)(umin ^ umax));
            unsigned mask = (hb == 31) ? 0xFFFFFFFFu : ((1u << (hb+1)) - 1u);
            unsigned P = umin & ~mask;
            for (int b = hb; b >= 0; --b){
                unsigned cand = P | (1u << b);
                int c = 0;
                #pragma unroll
                for (int k = 0; k < 64; ++k) c += (u[k] < cand) ? 1 : 0;
                #pragma unroll
                for (int o = 32; o; o >>= 1) c += __shfl_xor(c, o, 64);
                if (c <= 99) P = cand;
            }
            t = P;
        }
    }
    float tval = sqrtf(__uint_as_float(t));

    // ---- softmax denom over top-100 (tie multiplicity at t) ----
    float s = 0.f; int cl = 0;
    #pragma unroll
    for (int k = 0; k < 64; ++k){
        if (u[k] < t){ s += __expf(d0 - sqrtf(__uint_as_float(u[k]))); cl++; }
    }
    #pragma unroll
    for (int o = 32; o; o >>= 1){
        s += __shfl_xor(s, o, 64);
        cl += __shfl_xor(cl, o, 64);
    }
    if (lane == 0){
        float S = s + (float)(K_ - cl) * __expf(d0 - tval);
        float dcode = sqrtf(__uint_as_float(ucode));
        if (ucode > t) S += __expf(d0 - dcode) - __expf(d0 - tval);  // include_correct swap
        float nll = dcode - d0 + __logf(S);
        pairbuf[n] = make_float2(nll, (idx0 == code) ? 1.f : 0.f);
    }
}

__global__ __launch_bounds__(1024) void finalize_kernel(const float2* __restrict__ pair,
                                                        float* __restrict__ out){
    int tid = threadIdx.x;
    float sn = 0.f, sh = 0.f;
    for (int i = tid; i < N_; i += 1024){
        float2 p = pair[i]; sn += p.x; sh += p.y;
    }
    #pragma unroll
    for (int o = 32; o; o >>= 1){ sn += __shfl_down(sn, o, 64); sh += __shfl_down(sh, o, 64); }
    __shared__ float a[16], b[16];
    int wv = tid >> 6, lane = tid & 63;
    if (lane == 0){ a[wv] = sn; b[wv] = sh; }
    __syncthreads();
    if (tid == 0){
        float L = 0.f, H = 0.f;
        #pragma unroll
        for (int i = 0; i < 16; ++i){ L += a[i]; H += b[i]; }
        out[0] = L / (float)N_;
        out[1] = H / (float)N_;   // local prediction is always candidate 0
        out[2] = H / (float)N_;
        out[3] = 1.0f;            // include_correct guarantees membership
    }
}

// ---------------- launcher ----------------
extern "C" void kernel_launch(void* const* d_in, const int* in_sizes, int n_in,
                              void* d_out, int out_size, void* d_ws, size_t ws_size,
                              hipStream_t stream){
    const float* S   = (const float*)d_in[0];
    const int* codes = (const int*)d_in[1];
    const float* CB  = (const float*)d_in[2];
    float* out = (float*)d_out;

    char* w = (char*)d_ws;
    size_t off = 0;
    unsigned short* embT = (unsigned short*)(w + off); off += (size_t)NPAD_ * C_ * 2;
    unsigned short* CBh  = (unsigned short*)(w + off); off += (size_t)V_ * C_ * 2;
    float* csq = (float*)(w + off); off += (size_t)V_ * 4;
    float* esq = (float*)(w + off); off += (size_t)N_ * 4;
    off = (off + 255) & ~(size_t)255;
    float2* pairbuf = (float2*)(w + off); off += (size_t)N_ * 8;
    float* distbuf = (float*)(w + off);

    size_t avail = (ws_size > off) ? ws_size - off : 0;
    long maxrows = (long)(avail / ((size_t)V_ * 4));
    int chunk = (maxrows >= N_) ? N_ : (int)maxrows;
    if (chunk < 4) chunk = 4;

    hipMemsetAsync(esq, 0, (size_t)N_ * 4, stream);
    hipLaunchKernelGGL(cbconv_kernel, dim3(V_/4), dim3(256), 0, stream, CB, CBh, csq);
    hipLaunchKernelGGL(transpose_conv_kernel, dim3((T_+31)/32, C_/32, B_), dim3(32, 8), 0, stream,
                       S, embT, esq);

    for (int row_lo = 0; row_lo < N_; row_lo += chunk){
        int row_hi = row_lo + chunk; if (row_hi > N_) row_hi = N_;
        int rows = row_hi - row_lo;
        hipLaunchKernelGGL(gemm_d2_kernel, dim3((rows + 127)/128, V_/128), dim3(256), 0, stream,
                           embT, CBh, esq, csq, distbuf, row_lo, row_hi);
        hipLaunchKernelGGL(select_kernel, dim3((rows + 3)/4), dim3(256), 0, stream,
                           distbuf, codes, pairbuf, row_lo, rows);
    }
    hipLaunchKernelGGL(finalize_kernel, dim3(1), dim3(1024), 0, stream, pairbuf, out);
}

// Round 5
// 222.342 us; speedup vs baseline: 4.9754x; 1.2601x over previous
//
#include <hip/hip_runtime.h>
#include <hip/hip_bf16.h>
#include <cstdint>

#define B_ 8
#define C_ 512
#define T_ 1500
#define N_ (B_*T_)      // 12000 tokens
#define NPAD_ 12032     // 94*128
#define V_ 4096
#define K_ 100

typedef unsigned long long u64;
typedef __attribute__((ext_vector_type(8))) short short8;
typedef __attribute__((ext_vector_type(8))) unsigned short u16x8;
typedef __attribute__((ext_vector_type(4))) float f32x4;

__device__ __forceinline__ unsigned short f2bf(float x){
    __hip_bfloat16 h = __float2bfloat16(x);
    return __builtin_bit_cast(unsigned short, h);
}
__device__ __forceinline__ unsigned short f2h(float x){
    return __builtin_bit_cast(unsigned short, (_Float16)x);
}
__device__ __forceinline__ float h2f(unsigned short h){
    return (float)__builtin_bit_cast(_Float16, h);
}

__device__ __forceinline__ void gll16(const unsigned short* g, unsigned short* l){
    __builtin_amdgcn_global_load_lds(
        (const __attribute__((address_space(1))) void*)g,
        (__attribute__((address_space(3))) void*)l, 16, 0, 0);
}

// ---------------- codebook: fp32 -> bf16 + csq (fp32-exact) ----------------
__global__ __launch_bounds__(256) void cbconv_kernel(const float* __restrict__ CB,
                                                     unsigned short* __restrict__ CBh,
                                                     float* __restrict__ csq){
    int wv = threadIdx.x >> 6, lane = threadIdx.x & 63;
    int r = blockIdx.x * 4 + wv;
    const float4* p4 = (const float4*)(CB + (size_t)r * C_);
    ushort4* o4 = (ushort4*)(CBh + (size_t)r * C_);
    float s = 0.f;
    #pragma unroll
    for (int j = 0; j < 2; ++j){
        float4 v = p4[lane + j*64];
        s += v.x*v.x + v.y*v.y + v.z*v.z + v.w*v.w;
        ushort4 h; h.x = f2bf(v.x); h.y = f2bf(v.y); h.z = f2bf(v.z); h.w = f2bf(v.w);
        o4[lane + j*64] = h;
    }
    #pragma unroll
    for (int o = 32; o; o >>= 1) s += __shfl_down(s, o, 64);
    if (lane == 0) csq[r] = s;
}

// ---------------- student: (B,C,T) fp32 -> embT bf16 (N,C) + esq partials ----------------
__global__ __launch_bounds__(256) void transpose_conv_kernel(const float* __restrict__ S,
                                                             unsigned short* __restrict__ embT,
                                                             float* __restrict__ esq){
    __shared__ float tile[32][33];
    __shared__ float psum[8][33];
    int b  = blockIdx.z;
    int c0 = blockIdx.y * 32;
    int t0 = blockIdx.x * 32;
    int tx = threadIdx.x, ty = threadIdx.y; // 32 x 8
    #pragma unroll
    for (int r = 0; r < 4; ++r){
        int c = c0 + ty + r*8;
        int t = t0 + tx;
        tile[ty + r*8][tx] = (t < T_) ? S[((size_t)b*C_ + c)*T_ + t] : 0.f;
    }
    __syncthreads();
    float ps = 0.f;
    #pragma unroll
    for (int r = 0; r < 4; ++r){ float v = tile[ty + r*8][tx]; ps += v * v; }
    psum[ty][tx] = ps;
    #pragma unroll
    for (int r = 0; r < 4; ++r){
        int t = t0 + ty + r*8;
        int c = c0 + tx;
        if (t < T_) embT[((size_t)b*T_ + t)*C_ + c] = f2bf(tile[tx][ty + r*8]);
    }
    __syncthreads();
    if (ty == 0){
        int t = t0 + tx;
        if (t < T_){
            float s2 = 0.f;
            #pragma unroll
            for (int w = 0; w < 8; ++w) s2 += psum[w][tx];
            atomicAdd(&esq[b*T_ + t], s2);
        }
    }
}

// ---------------- bf16 MFMA GEMM -> fp16 dot matrix ----------------
__global__ __launch_bounds__(256) void gemm_dot_kernel(
    const unsigned short* __restrict__ A, const unsigned short* __restrict__ Bm,
    unsigned short* __restrict__ doth, int row_lo, int row_hi)
{
    __shared__ unsigned short As[128*32];
    __shared__ unsigned short Bs[128*32];
    int tid = threadIdx.x, lane = tid & 63, wv = tid >> 6;
    int row0 = row_lo + blockIdx.x * 128;
    int col0 = blockIdx.y * 128;

    int sr = lane >> 2;
    int sk = (lane & 3) * 8;
    int ar0 = row0 + wv*32 + sr;       int ar1 = ar0 + 16;
    int ca0 = (ar0 < N_) ? ar0 : N_-1; int ca1 = (ar1 < N_) ? ar1 : N_-1;
    const unsigned short* Ap0 = A  + (size_t)ca0 * C_ + sk;
    const unsigned short* Ap1 = A  + (size_t)ca1 * C_ + sk;
    const unsigned short* Bp0 = Bm + (size_t)(col0 + wv*32 + sr) * C_ + sk;
    const unsigned short* Bp1 = Bp0 + (size_t)16 * C_;
    unsigned short* Ad0 = &As[(wv*32     ) * 32];
    unsigned short* Ad1 = &As[(wv*32 + 16) * 32];
    unsigned short* Bd0 = &Bs[(wv*32     ) * 32];
    unsigned short* Bd1 = &Bs[(wv*32 + 16) * 32];

    int wm = (wv >> 1) * 64, wn = (wv & 1) * 64;
    int fr = lane & 15;
    int fk = (lane >> 4) * 8;

    f32x4 acc[4][4];
    #pragma unroll
    for (int i = 0; i < 4; ++i)
        #pragma unroll
        for (int j = 0; j < 4; ++j) acc[i][j] = (f32x4){0.f, 0.f, 0.f, 0.f};

    for (int kt = 0; kt < C_/32; ++kt){
        int k0 = kt * 32;
        gll16(Ap0 + k0, Ad0);
        gll16(Ap1 + k0, Ad1);
        gll16(Bp0 + k0, Bd0);
        gll16(Bp1 + k0, Bd1);
        __syncthreads();
        short8 af[4], bf[4];
        #pragma unroll
        for (int i = 0; i < 4; ++i) af[i] = *(const short8*)&As[(wm + i*16 + fr)*32 + fk];
        #pragma unroll
        for (int j = 0; j < 4; ++j) bf[j] = *(const short8*)&Bs[(wn + j*16 + fr)*32 + fk];
        #pragma unroll
        for (int i = 0; i < 4; ++i)
            #pragma unroll
            for (int j = 0; j < 4; ++j)
                acc[i][j] = __builtin_amdgcn_mfma_f32_16x16x32_bf16(af[i], bf[j], acc[i][j], 0, 0, 0);
        __syncthreads();
    }

    int er = (lane >> 4) * 4;
    int ec = lane & 15;
    #pragma unroll
    for (int i = 0; i < 4; ++i){
        #pragma unroll
        for (int r = 0; r < 4; ++r){
            int n = row0 + wm + i*16 + er + r;
            if (n >= row_hi) continue;
            size_t base = (size_t)(n - row_lo) * V_;
            #pragma unroll
            for (int j = 0; j < 4; ++j){
                int v = col0 + wn + j*16 + ec;
                doth[base + v] = f2h(acc[i][j][r]);
            }
        }
    }
}

// ---------------- selection v4: wave/row, fp16 dot input, no spills ----------------
__global__ __launch_bounds__(256, 2) void select_kernel(const unsigned short* __restrict__ doth,
                                                        const int* __restrict__ codes,
                                                        const float* __restrict__ esq,
                                                        const float* __restrict__ csq,
                                                        float2* __restrict__ pairbuf,
                                                        int row_lo, int nrows){
    int tid = threadIdx.x, lane = tid & 63, wv = tid >> 6;
    int lrow = blockIdx.x * 4 + wv;
    if (lrow >= nrows) return;               // wave-uniform, no barriers below
    int n = row_lo + lrow;
    const u16x8* r8 = (const u16x8*)(doth + (size_t)lrow * V_);

    __shared__ unsigned hist[4][256] __attribute__((aligned(16)));
    __shared__ unsigned coll[4][64];
    __shared__ unsigned collcnt[4];

    float esq_n = esq[n];
    int code = codes[n];
    float dotc = h2f(doth[(size_t)lrow * V_ + code]);
    unsigned ucode = __float_as_uint(fmaxf(esq_n + csq[code] - 2.f * dotc, 0.f));

    // ---- load + reconstruct d2 bits: u[64] is the only big live array ----
    unsigned u[64];
    #pragma unroll
    for (int j = 0; j < 8; ++j){
        u16x8 h = r8[lane + j*64];
        const float4* cp = (const float4*)(csq + 8*lane + 512*j);
        float4 c0 = cp[0], c1 = cp[1];
        float cs[8] = {c0.x, c0.y, c0.z, c0.w, c1.x, c1.y, c1.z, c1.w};
        #pragma unroll
        for (int e = 0; e < 8; ++e){
            float d2 = fmaxf(esq_n + cs[e] - 2.f * h2f(h[e]), 0.f);
            u[8*j+e] = __float_as_uint(d2);
        }
    }

    // ---- min/max (uint order == float order, all >= 0) ----
    unsigned umin = u[0], umax = u[0];
    #pragma unroll
    for (int k = 1; k < 64; ++k){
        umin = (u[k] < umin) ? u[k] : umin;
        umax = (u[k] > umax) ? u[k] : umax;
    }
    #pragma unroll
    for (int o = 32; o; o >>= 1){
        unsigned a = (unsigned)__shfl_xor((int)umin, o, 64); if (a < umin) umin = a;
        unsigned b = (unsigned)__shfl_xor((int)umax, o, 64); if (b > umax) umax = b;
    }
    // ---- argmin (lowest index among value==umin); v = 8*lane + 512*(k>>3) + (k&7) ----
    unsigned im = 0xFFFFFFFFu;
    #pragma unroll
    for (int k = 0; k < 64; ++k){
        unsigned idx = 8u*(unsigned)lane + (unsigned)(512*(k >> 3) + (k & 7));
        if (u[k] == umin && idx < im) im = idx;
    }
    #pragma unroll
    for (int o = 32; o; o >>= 1){
        unsigned a = (unsigned)__shfl_xor((int)im, o, 64); if (a < im) im = a;
    }
    int idx0 = (int)im;
    float d0 = sqrtf(__uint_as_float(umin));

    // ---- rank-99 threshold t via per-wave histogram + in-bin bitwise search ----
    unsigned t;
    if (umin == umax){
        t = umin;
    } else {
        ((uint4*)&hist[wv][0])[lane] = (uint4){0u,0u,0u,0u};
        if (lane == 0) collcnt[wv] = 0u;
        asm volatile("s_waitcnt lgkmcnt(0)" ::: "memory");
        float fmn = __uint_as_float(umin), fmx = __uint_as_float(umax);
        float invw = 256.0f / (fmx - fmn);
        #pragma unroll
        for (int k = 0; k < 64; ++k){
            float fk = __uint_as_float(u[k]);
            int b = (int)((fk - fmn) * invw); b = (b > 255) ? 255 : b;
            atomicAdd(&hist[wv][b], 1u);
        }
        asm volatile("s_waitcnt lgkmcnt(0)" ::: "memory");
        uint4 hq = ((uint4*)&hist[wv][0])[lane];
        unsigned lsum = hq.x + hq.y + hq.z + hq.w;
        unsigned inc = lsum;
        #pragma unroll
        for (int o = 1; o < 64; o <<= 1){
            unsigned y = (unsigned)__shfl_up((int)inc, o, 64);
            if (lane >= o) inc += y;
        }
        unsigned e0 = inc - lsum;
        unsigned e1 = e0 + hq.x, e2 = e1 + hq.y, e3 = e2 + hq.z, e4 = e3 + hq.w;
        int sel = -1;
        if      (e0 <= 99u && 99u < e1) sel = 0;
        else if (e1 <= 99u && 99u < e2) sel = 1;
        else if (e2 <= 99u && 99u < e3) sel = 2;
        else if (e3 <= 99u && 99u < e4) sel = 3;
        u64 bal = __ballot(sel >= 0);
        int src = __ffsll(bal) - 1;
        unsigned myBk = (unsigned)(4*lane + (sel < 0 ? 0 : sel));
        unsigned myBase = (sel == 1) ? e1 : (sel == 2) ? e2 : (sel == 3) ? e3 : e0;
        int Bk   = __shfl((int)myBk,   src, 64);
        int base = __shfl((int)myBase, src, 64);
        int rk = 99 - base;
        #pragma unroll
        for (int k = 0; k < 64; ++k){
            float fk = __uint_as_float(u[k]);
            int b = (int)((fk - fmn) * invw); b = (b > 255) ? 255 : b;
            if (b == Bk){
                unsigned pos = atomicAdd(&collcnt[wv], 1u);
                if (pos < 64u) coll[wv][pos] = u[k];
            }
        }
        asm volatile("s_waitcnt lgkmcnt(0)" ::: "memory");
        unsigned bcnt = collcnt[wv];
        if (bcnt <= 64u){
            unsigned w = (lane < (int)bcnt) ? coll[wv][lane] : 0xFFFFFFFFu;
            unsigned wmn = (lane < (int)bcnt) ? w : 0xFFFFFFFFu;
            unsigned wmx = (lane < (int)bcnt) ? w : 0u;
            #pragma unroll
            for (int o = 32; o; o >>= 1){
                unsigned a = (unsigned)__shfl_xor((int)wmn, o, 64); if (a < wmn) wmn = a;
                unsigned b = (unsigned)__shfl_xor((int)wmx, o, 64); if (b > wmx) wmx = b;
            }
            unsigned P;
            if (wmn == wmx) P = wmn;
            else {
                int hb = 31 - __clz((int)(wmn ^ wmx));
                unsigned mask = (hb == 31) ? 0xFFFFFFFFu : ((1u << (hb+1)) - 1u);
                P = wmn & ~mask;
                for (int b = hb; b >= 0; --b){
                    unsigned cand = P | (1u << b);
                    int c = __popcll(__ballot(w < cand));
                    if (c <= rk) P = cand;
                }
            }
            t = P;
        } else {
            int hb = 31 - __clz((int)(umin ^ umax));
            unsigned mask = (hb == 31) ? 0xFFFFFFFFu : ((1u << (hb+1)) - 1u);
            unsigned P = umin & ~mask;
            for (int b = hb; b >= 0; --b){
                unsigned cand = P | (1u << b);
                int c = 0;
                #pragma unroll
                for (int k = 0; k < 64; ++k) c += (u[k] < cand) ? 1 : 0;
                #pragma unroll
                for (int o = 32; o; o >>= 1) c += __shfl_xor(c, o, 64);
                if (c <= 99) P = cand;
            }
            t = P;
        }
    }
    float tval = sqrtf(__uint_as_float(t));

    // ---- softmax denom over top-100 (tie multiplicity at t) ----
    float s = 0.f; int cl = 0;
    #pragma unroll
    for (int k = 0; k < 64; ++k){
        if (u[k] < t){ s += __expf(d0 - sqrtf(__uint_as_float(u[k]))); cl++; }
    }
    #pragma unroll
    for (int o = 32; o; o >>= 1){
        s += __shfl_xor(s, o, 64);
        cl += __shfl_xor(cl, o, 64);
    }
    if (lane == 0){
        float S = s + (float)(K_ - cl) * __expf(d0 - tval);
        float dcode = sqrtf(__uint_as_float(ucode));
        if (ucode > t) S += __expf(d0 - dcode) - __expf(d0 - tval);  // include_correct swap
        float nll = dcode - d0 + __logf(S);
        pairbuf[n] = make_float2(nll, (idx0 == code) ? 1.f : 0.f);
    }
}

__global__ __launch_bounds__(1024) void finalize_kernel(const float2* __restrict__ pair,
                                                        float* __restrict__ out){
    int tid = threadIdx.x;
    float sn = 0.f, sh = 0.f;
    for (int i = tid; i < N_; i += 1024){
        float2 p = pair[i]; sn += p.x; sh += p.y;
    }
    #pragma unroll
    for (int o = 32; o; o >>= 1){ sn += __shfl_down(sn, o, 64); sh += __shfl_down(sh, o, 64); }
    __shared__ float a[16], b[16];
    int wv = tid >> 6, lane = tid & 63;
    if (lane == 0){ a[wv] = sn; b[wv] = sh; }
    __syncthreads();
    if (tid == 0){
        float L = 0.f, H = 0.f;
        #pragma unroll
        for (int i = 0; i < 16; ++i){ L += a[i]; H += b[i]; }
        out[0] = L / (float)N_;
        out[1] = H / (float)N_;   // local prediction is always candidate 0
        out[2] = H / (float)N_;
        out[3] = 1.0f;            // include_correct guarantees membership
    }
}

// ---------------- launcher ----------------
extern "C" void kernel_launch(void* const* d_in, const int* in_sizes, int n_in,
                              void* d_out, int out_size, void* d_ws, size_t ws_size,
                              hipStream_t stream){
    const float* S   = (const float*)d_in[0];
    const int* codes = (const int*)d_in[1];
    const float* CB  = (const float*)d_in[2];
    float* out = (float*)d_out;

    char* w = (char*)d_ws;
    size_t off = 0;
    unsigned short* embT = (unsigned short*)(w + off); off += (size_t)NPAD_ * C_ * 2;
    unsigned short* CBh  = (unsigned short*)(w + off); off += (size_t)V_ * C_ * 2;
    float* csq = (float*)(w + off); off += (size_t)V_ * 4;
    float* esq = (float*)(w + off); off += (size_t)N_ * 4;
    off = (off + 255) & ~(size_t)255;
    float2* pairbuf = (float2*)(w + off); off += (size_t)N_ * 8;
    unsigned short* dotbuf = (unsigned short*)(w + off);

    size_t avail = (ws_size > off) ? ws_size - off : 0;
    long maxrows = (long)(avail / ((size_t)V_ * 2));
    int chunk = (maxrows >= N_) ? N_ : (int)maxrows;
    if (chunk < 4) chunk = 4;

    hipMemsetAsync(esq, 0, (size_t)N_ * 4, stream);
    hipLaunchKernelGGL(cbconv_kernel, dim3(V_/4), dim3(256), 0, stream, CB, CBh, csq);
    hipLaunchKernelGGL(transpose_conv_kernel, dim3((T_+31)/32, C_/32, B_), dim3(32, 8), 0, stream,
                       S, embT, esq);

    for (int row_lo = 0; row_lo < N_; row_lo += chunk){
        int row_hi = row_lo + chunk; if (row_hi > N_) row_hi = N_;
        int rows = row_hi - row_lo;
        hipLaunchKernelGGL(gemm_dot_kernel, dim3((rows + 127)/128, V_/128), dim3(256), 0, stream,
                           embT, CBh, dotbuf, row_lo, row_hi);
        hipLaunchKernelGGL(select_kernel, dim3((rows + 3)/4), dim3(256), 0, stream,
                           dotbuf, codes, esq, csq, pairbuf, row_lo, rows);
    }
    hipLaunchKernelGGL(finalize_kernel, dim3(1), dim3(1024), 0, stream, pairbuf, out);
}